// Round 5
// baseline (266.525 us; speedup 1.0000x reference)
//
#include <hip/hip_runtime.h>
#include <hip/hip_bf16.h>

#define S_DIM 2048
#define B_DIM 2
#define E_DIM 1024
#define H_DIM 16
#define M_ROWS 4096

typedef __attribute__((ext_vector_type(8))) short bf16x8;
typedef __attribute__((ext_vector_type(4))) float f32x4;

__device__ inline unsigned short f2bf(float x) {
    unsigned int b = __float_as_uint(x);
    return (unsigned short)((b + 0x7fffu + ((b >> 16) & 1u)) >> 16);  // RNE
}

// ---------------- prep: cast X to bf16 ----------------
__global__ __launch_bounds__(256) void cast_x(const float* __restrict__ X,
                                              unsigned short* __restrict__ Xb) {
    int g = blockIdx.x * 256 + threadIdx.x;
    const float4* src = reinterpret_cast<const float4*>(X) + (size_t)g * 2;
    float4 v0 = src[0], v1 = src[1];
    union { unsigned short h[8]; int4 v; } u;
    u.h[0] = f2bf(v0.x); u.h[1] = f2bf(v0.y); u.h[2] = f2bf(v0.z); u.h[3] = f2bf(v0.w);
    u.h[4] = f2bf(v1.x); u.h[5] = f2bf(v1.y); u.h[6] = f2bf(v1.z); u.h[7] = f2bf(v1.w);
    *reinterpret_cast<int4*>(Xb + (size_t)g * 8) = u.v;
}

// ---------------- prep: Wt[n][k] = bf16(W[k][n]) ----------------
__global__ __launch_bounds__(256) void transpose_cast(
        const float* __restrict__ Wq, const float* __restrict__ Wk,
        const float* __restrict__ Wv, const float* __restrict__ Wo,
        unsigned short* __restrict__ Wqt, unsigned short* __restrict__ Wkt,
        unsigned short* __restrict__ Wvt, unsigned short* __restrict__ Wot) {
    const float* W = (blockIdx.z == 0) ? Wq : (blockIdx.z == 1) ? Wk
                   : (blockIdx.z == 2) ? Wv : Wo;
    unsigned short* Wt = (blockIdx.z == 0) ? Wqt : (blockIdx.z == 1) ? Wkt
                       : (blockIdx.z == 2) ? Wvt : Wot;
    __shared__ float T[64][65];
    const int t = threadIdx.x;
    const int k0 = blockIdx.x * 64, n0 = blockIdx.y * 64;
#pragma unroll
    for (int p = 0; p < 4; ++p) {
        int r = p * 16 + (t >> 4), c4 = (t & 15) * 4;
        float4 v = *reinterpret_cast<const float4*>(&W[(size_t)(k0 + r) * E_DIM + n0 + c4]);
        T[r][c4] = v.x; T[r][c4 + 1] = v.y; T[r][c4 + 2] = v.z; T[r][c4 + 3] = v.w;
    }
    __syncthreads();
    const int nl = t >> 2, ks = (t & 3) * 16;
    union { unsigned short h[16]; int4 v[2]; } u;
#pragma unroll
    for (int i = 0; i < 16; ++i) u.h[i] = f2bf(T[ks + i][nl]);
    int4* dst = reinterpret_cast<int4*>(&Wt[(size_t)(n0 + nl) * E_DIM + k0 + ks]);
    dst[0] = u.v[0]; dst[1] = u.v[1];
}

// ---------------- shared GEMM body: 128x128 tile, BK=64, 4 waves ----------------
// A [M][1024] bf16 row-major, Bt [N][1024] bf16 row-major (= B^T).
// LDS tiles [128 rows][64 k] bf16, XOR-swizzled at 16B-slot granularity.
#define GEMM_BODY                                                                          \
    __shared__ int4 smem_i4[2048];                                                         \
    char* sm = reinterpret_cast<char*>(smem_i4);                                           \
    char* smA = sm; char* smB = sm + 16384;                                                \
    const int tid = threadIdx.x; const int lane = tid & 63; const int wid = tid >> 6;      \
    const int wr = (wid >> 1) * 64, wc = (wid & 1) * 64;                                   \
    const int r0 = blockIdx.x * 128, n0 = blockIdx.y * 128;                                \
    f32x4 acc[4][4] = {};                                                                  \
    const int srow = tid >> 3, sslot = tid & 7;                                            \
    for (int k0 = 0; k0 < E_DIM; k0 += 64) {                                               \
        __syncthreads();                                                                   \
        _Pragma("unroll") for (int p = 0; p < 4; ++p) {                                    \
            int row = p * 32 + srow;                                                       \
            int4 va = *reinterpret_cast<const int4*>(&A[(size_t)(r0 + row) * E_DIM + k0 + sslot * 8]); \
            *reinterpret_cast<int4*>(smA + row * 128 + ((sslot ^ (row & 7)) << 4)) = va;   \
            int4 vb = *reinterpret_cast<const int4*>(&Bt[(size_t)(n0 + row) * E_DIM + k0 + sslot * 8]); \
            *reinterpret_cast<int4*>(smB + row * 128 + ((sslot ^ (row & 7)) << 4)) = vb;   \
        }                                                                                  \
        __syncthreads();                                                                   \
        _Pragma("unroll") for (int ks = 0; ks < 2; ++ks) {                                 \
            bf16x8 af[4], bfr[4];                                                          \
            _Pragma("unroll") for (int f = 0; f < 4; ++f) {                                \
                int ra = wr + f * 16 + (lane & 15);                                        \
                af[f] = *reinterpret_cast<bf16x8*>(smA + ra * 128 + (((ks * 4 + (lane >> 4)) ^ (ra & 7)) << 4)); \
                int rb = wc + f * 16 + (lane & 15);                                        \
                bfr[f] = *reinterpret_cast<bf16x8*>(smB + rb * 128 + (((ks * 4 + (lane >> 4)) ^ (rb & 7)) << 4)); \
            }                                                                              \
            _Pragma("unroll") for (int i = 0; i < 4; ++i)                                  \
                _Pragma("unroll") for (int j = 0; j < 4; ++j)                              \
                    acc[i][j] = __builtin_amdgcn_mfma_f32_16x16x32_bf16(af[i], bfr[j], acc[i][j], 0, 0, 0); \
        }                                                                                  \
    }

// QKV: A rows r = s*B+b. z selects W and output. Q,K stored [b][h][s][d] bf16;
// V stored transposed [b][h][d][s] bf16 (so PV's B-operand has contiguous k=j).
__global__ __launch_bounds__(256) void gemm_qkv(
        const unsigned short* __restrict__ A,
        const unsigned short* __restrict__ Wqt, const unsigned short* __restrict__ Wkt,
        const unsigned short* __restrict__ Wvt,
        unsigned short* __restrict__ Q, unsigned short* __restrict__ K,
        unsigned short* __restrict__ Vt) {
    const unsigned short* Bt = (blockIdx.z == 0) ? Wqt : (blockIdx.z == 1) ? Wkt : Wvt;
    GEMM_BODY
    unsigned short* O = (blockIdx.z == 0) ? Q : (blockIdx.z == 1) ? K : Vt;
    const int mode = blockIdx.z;
#pragma unroll
    for (int i = 0; i < 4; ++i)
#pragma unroll
    for (int j = 0; j < 4; ++j)
#pragma unroll
    for (int q = 0; q < 4; ++q) {
        int row = r0 + wr + i * 16 + (lane >> 4) * 4 + q;   // = s*2 + b
        int col = n0 + wc + j * 16 + (lane & 15);           // = h*64 + d
        int s = row >> 1, b = row & 1, h = col >> 6, d = col & 63;
        unsigned short v = f2bf(acc[i][j][q]);
        if (mode < 2) O[(((size_t)(b * H_DIM + h)) * S_DIM + s) * 64 + d] = v;
        else          O[(((size_t)(b * H_DIM + h)) * 64 + d) * S_DIM + s] = v;
    }
}

// out-proj: A = ctx bf16 [b*2048+s][1024]; out fp32 [(s*B+b)*E + e]
__global__ __launch_bounds__(256) void gemm_out(
        const unsigned short* __restrict__ A,
        const unsigned short* __restrict__ Bt, float* __restrict__ out) {
    GEMM_BODY
#pragma unroll
    for (int i = 0; i < 4; ++i)
#pragma unroll
    for (int j = 0; j < 4; ++j)
#pragma unroll
    for (int q = 0; q < 4; ++q) {
        int row = r0 + wr + i * 16 + (lane >> 4) * 4 + q;   // = b*2048 + s
        int b = row >> 11, s = row & 2047;
        int col = n0 + wc + j * 16 + (lane & 15);
        out[((size_t)(s * B_DIM + b)) * E_DIM + col] = acc[i][j][q];
    }
}

// ---------------- flash attention, bf16 MFMA ----------------
// 256 thr = 4 waves; wave owns 32 q-rows; KV tile 64; Q in regs; K/Vt in LDS
// (XOR-swizzled); P via per-wave swizzled LDS round-trip.
__global__ __launch_bounds__(256) void attn(
        const unsigned short* __restrict__ Q, const unsigned short* __restrict__ K,
        const unsigned short* __restrict__ Vt, unsigned short* __restrict__ ctx) {
    __shared__ int4 smem_i4[2048];
    char* sm = reinterpret_cast<char*>(smem_i4);
    char* smK = sm; char* smV = sm + 8192; char* smP = sm + 16384;
    const int tid = threadIdx.x, lane = tid & 63, wid = tid >> 6;
    const int bh = blockIdx.y;
    const int i0 = blockIdx.x * 128;
    const unsigned short* Qb = Q + (size_t)bh * S_DIM * 64;
    const unsigned short* Kb = K + (size_t)bh * S_DIM * 64;
    const unsigned short* Vb = Vt + (size_t)bh * 64 * S_DIM;
    char* smPw = smP + wid * 4096;

    bf16x8 qf[2][2];
#pragma unroll
    for (int mf = 0; mf < 2; ++mf)
#pragma unroll
    for (int ks = 0; ks < 2; ++ks) {
        int qrow = i0 + wid * 32 + mf * 16 + (lane & 15);
        qf[mf][ks] = *reinterpret_cast<const bf16x8*>(
            &Qb[(size_t)qrow * 64 + ks * 32 + (lane >> 4) * 8]);
    }

    f32x4 o[2][4] = {};
    float mrun[2][4], lrun[2][4];
#pragma unroll
    for (int mf = 0; mf < 2; ++mf)
#pragma unroll
    for (int q = 0; q < 4; ++q) { mrun[mf][q] = -INFINITY; lrun[mf][q] = 0.f; }

    const int srow = tid >> 3, sslot = tid & 7;

    for (int j0 = 0; j0 < S_DIM; j0 += 64) {
        __syncthreads();
#pragma unroll
        for (int p = 0; p < 2; ++p) {
            int row = p * 32 + srow;
            int4 vk = *reinterpret_cast<const int4*>(&Kb[(size_t)(j0 + row) * 64 + sslot * 8]);
            *reinterpret_cast<int4*>(smK + row * 128 + ((sslot ^ (row & 7)) << 4)) = vk;
            int4 vv = *reinterpret_cast<const int4*>(&Vb[(size_t)row * S_DIM + j0 + sslot * 8]);
            *reinterpret_cast<int4*>(smV + row * 128 + ((sslot ^ (row & 7)) << 4)) = vv;
        }
        __syncthreads();

        // QK^T
        f32x4 sv[2][4] = {};
#pragma unroll
        for (int ks = 0; ks < 2; ++ks) {
            bf16x8 kf[4];
#pragma unroll
            for (int jf = 0; jf < 4; ++jf) {
                int r = jf * 16 + (lane & 15);
                kf[jf] = *reinterpret_cast<bf16x8*>(
                    smK + r * 128 + (((ks * 4 + (lane >> 4)) ^ (r & 7)) << 4));
            }
#pragma unroll
            for (int mf = 0; mf < 2; ++mf)
#pragma unroll
            for (int jf = 0; jf < 4; ++jf)
                sv[mf][jf] = __builtin_amdgcn_mfma_f32_16x16x32_bf16(
                    qf[mf][ks], kf[jf], sv[mf][jf], 0, 0, 0);
        }

        // online softmax (rows: reg q + lane>>4 group; cols: lane&15 + jf)
#pragma unroll
        for (int mf = 0; mf < 2; ++mf) {
#pragma unroll
            for (int jf = 0; jf < 4; ++jf) sv[mf][jf] *= 0.125f;
            float ml[4];
#pragma unroll
            for (int q = 0; q < 4; ++q)
                ml[q] = fmaxf(fmaxf(sv[mf][0][q], sv[mf][1][q]),
                              fmaxf(sv[mf][2][q], sv[mf][3][q]));
#pragma unroll
            for (int st = 1; st < 16; st <<= 1)
#pragma unroll
                for (int q = 0; q < 4; ++q)
                    ml[q] = fmaxf(ml[q], __shfl_xor(ml[q], st));
#pragma unroll
            for (int q = 0; q < 4; ++q) {
                float mn = fmaxf(mrun[mf][q], ml[q]);
                float al = __expf(mrun[mf][q] - mn);
                mrun[mf][q] = mn;
                lrun[mf][q] *= al;
#pragma unroll
                for (int df = 0; df < 4; ++df) o[mf][df][q] *= al;
            }
            float ls[4] = {0.f, 0.f, 0.f, 0.f};
#pragma unroll
            for (int jf = 0; jf < 4; ++jf)
#pragma unroll
                for (int q = 0; q < 4; ++q) {
                    float p = __expf(sv[mf][jf][q] - mrun[mf][q]);
                    ls[q] += p;
                    int row = mf * 16 + (lane >> 4) * 4 + q;
                    int cb = (jf * 32 + (lane & 15) * 2) ^ ((row & 7) << 4);
                    *reinterpret_cast<unsigned short*>(smPw + row * 128 + cb) = f2bf(p);
                }
#pragma unroll
            for (int st = 1; st < 16; st <<= 1)
#pragma unroll
                for (int q = 0; q < 4; ++q) ls[q] += __shfl_xor(ls[q], st);
#pragma unroll
            for (int q = 0; q < 4; ++q) lrun[mf][q] += ls[q];
        }

        // PV (A = P from per-wave LDS, B^T = Vt rows)
#pragma unroll
        for (int ks = 0; ks < 2; ++ks) {
            bf16x8 pf[2], vf[4];
#pragma unroll
            for (int mf = 0; mf < 2; ++mf) {
                int r = mf * 16 + (lane & 15);
                pf[mf] = *reinterpret_cast<bf16x8*>(
                    smPw + r * 128 + (((ks * 4 + (lane >> 4)) ^ (r & 7)) << 4));
            }
#pragma unroll
            for (int df = 0; df < 4; ++df) {
                int r = df * 16 + (lane & 15);
                vf[df] = *reinterpret_cast<bf16x8*>(
                    smV + r * 128 + (((ks * 4 + (lane >> 4)) ^ (r & 7)) << 4));
            }
#pragma unroll
            for (int mf = 0; mf < 2; ++mf)
#pragma unroll
            for (int df = 0; df < 4; ++df)
                o[mf][df] = __builtin_amdgcn_mfma_f32_16x16x32_bf16(
                    pf[mf], vf[df], o[mf][df], 0, 0, 0);
        }
    }

    // epilogue: ctx [b*2048+s][h*64+dv] bf16
    const int b = bh >> 4, h = bh & 15;
#pragma unroll
    for (int mf = 0; mf < 2; ++mf)
#pragma unroll
    for (int q = 0; q < 4; ++q) {
        float inv = 1.0f / lrun[mf][q];
        int row = i0 + wid * 32 + mf * 16 + (lane >> 4) * 4 + q;
#pragma unroll
        for (int df = 0; df < 4; ++df) {
            int col = h * 64 + df * 16 + (lane & 15);
            ctx[((size_t)(b * S_DIM + row)) * E_DIM + col] = f2bf(o[mf][df][q] * inv);
        }
    }
}

extern "C" void kernel_launch(void* const* d_in, const int* in_sizes, int n_in,
                              void* d_out, int out_size, void* d_ws, size_t ws_size,
                              hipStream_t stream) {
    const float* X  = (const float*)d_in[0];
    const float* Wq = (const float*)d_in[1];
    const float* Wk = (const float*)d_in[2];
    const float* Wv = (const float*)d_in[3];
    const float* Wo = (const float*)d_in[4];
    float* out = (float*)d_out;

    char* ws = (char*)d_ws;
    const size_t MB = (size_t)1 << 20;
    unsigned short* Xb  = (unsigned short*)(ws);            //  8 MB
    unsigned short* Wqt = (unsigned short*)(ws +  8 * MB);  //  2 MB
    unsigned short* Wkt = (unsigned short*)(ws + 10 * MB);
    unsigned short* Wvt = (unsigned short*)(ws + 12 * MB);
    unsigned short* Wot = (unsigned short*)(ws + 14 * MB);
    unsigned short* Qb  = (unsigned short*)(ws + 16 * MB);  //  8 MB each
    unsigned short* Kb  = (unsigned short*)(ws + 24 * MB);
    unsigned short* Vt  = (unsigned short*)(ws + 32 * MB);
    unsigned short* ctx = (unsigned short*)(ws + 40 * MB);  // ends at 48 MB

    cast_x<<<dim3(2048), 256, 0, stream>>>(X, Xb);
    transpose_cast<<<dim3(16, 16, 4), 256, 0, stream>>>(Wq, Wk, Wv, Wo, Wqt, Wkt, Wvt, Wot);
    gemm_qkv<<<dim3(32, 8, 3), 256, 0, stream>>>(Xb, Wqt, Wkt, Wvt, Qb, Kb, Vt);
    attn<<<dim3(16, 32), 256, 0, stream>>>(Qb, Kb, Vt, ctx);
    gemm_out<<<dim3(32, 8), 256, 0, stream>>>(ctx, Wot, out);
}

// Round 7
// 254.236 us; speedup vs baseline: 1.0483x; 1.0483x over previous
//
#include <hip/hip_runtime.h>
#include <hip/hip_bf16.h>

#define S_DIM 2048
#define B_DIM 2
#define E_DIM 1024
#define H_DIM 16
#define M_ROWS 4096

typedef __attribute__((ext_vector_type(8))) short bf16x8;
typedef __attribute__((ext_vector_type(4))) float f32x4;

__device__ inline unsigned short f2bf(float x) {
    unsigned int b = __float_as_uint(x);
    return (unsigned short)((b + 0x7fffu + ((b >> 16) & 1u)) >> 16);  // RNE
}

// async global->LDS, 16B per lane; dest must be wave-uniform base + lane*16
#define GLD_LDS16(gsrc, ldst)                                                              \
    __builtin_amdgcn_global_load_lds((const __attribute__((address_space(1))) void*)(gsrc), \
                                     (__attribute__((address_space(3))) void*)(ldst), 16, 0, 0)

// ---------------- prep: cast X to bf16 ----------------
__global__ __launch_bounds__(256) void cast_x(const float* __restrict__ X,
                                              unsigned short* __restrict__ Xb) {
    int g = blockIdx.x * 256 + threadIdx.x;
    const float4* src = reinterpret_cast<const float4*>(X) + (size_t)g * 2;
    float4 v0 = src[0], v1 = src[1];
    union { unsigned short h[8]; int4 v; } u;
    u.h[0] = f2bf(v0.x); u.h[1] = f2bf(v0.y); u.h[2] = f2bf(v0.z); u.h[3] = f2bf(v0.w);
    u.h[4] = f2bf(v1.x); u.h[5] = f2bf(v1.y); u.h[6] = f2bf(v1.z); u.h[7] = f2bf(v1.w);
    *reinterpret_cast<int4*>(Xb + (size_t)g * 8) = u.v;
}

// ---------------- prep: Wt[n][k] = bf16(W[k][n]) ----------------
__global__ __launch_bounds__(256) void transpose_cast(
        const float* __restrict__ Wq, const float* __restrict__ Wk,
        const float* __restrict__ Wv, const float* __restrict__ Wo,
        unsigned short* __restrict__ Wqt, unsigned short* __restrict__ Wkt,
        unsigned short* __restrict__ Wvt, unsigned short* __restrict__ Wot) {
    const float* W = (blockIdx.z == 0) ? Wq : (blockIdx.z == 1) ? Wk
                   : (blockIdx.z == 2) ? Wv : Wo;
    unsigned short* Wt = (blockIdx.z == 0) ? Wqt : (blockIdx.z == 1) ? Wkt
                       : (blockIdx.z == 2) ? Wvt : Wot;
    __shared__ float T[64][65];
    const int t = threadIdx.x;
    const int k0 = blockIdx.x * 64, n0 = blockIdx.y * 64;
#pragma unroll
    for (int p = 0; p < 4; ++p) {
        int r = p * 16 + (t >> 4), c4 = (t & 15) * 4;
        float4 v = *reinterpret_cast<const float4*>(&W[(size_t)(k0 + r) * E_DIM + n0 + c4]);
        T[r][c4] = v.x; T[r][c4 + 1] = v.y; T[r][c4 + 2] = v.z; T[r][c4 + 3] = v.w;
    }
    __syncthreads();
    const int nl = t >> 2, ks = (t & 3) * 16;
    union { unsigned short h[16]; int4 v[2]; } u;
#pragma unroll
    for (int i = 0; i < 16; ++i) u.h[i] = f2bf(T[ks + i][nl]);
    int4* dst = reinterpret_cast<int4*>(&Wt[(size_t)(n0 + nl) * E_DIM + k0 + ks]);
    dst[0] = u.v[0]; dst[1] = u.v[1];
}

// ---------------- shared GEMM body: 128x128 tile, BK=64, 4 waves ----------------
// A [M][1024] bf16 row-major, Bt [N][1024] bf16 row-major (= B^T).
// LDS tiles [128 rows][64 k] bf16, XOR-swizzled at 16B-slot granularity.
// Staging: global_load_lds width=16, linear LDS dest (= base + tid*16),
// inverse-swizzled global source column so the swizzled READ returns A[row][kslot*8..].
#define GEMM_BODY                                                                          \
    __shared__ int4 smem_i4[2048];                                                         \
    char* sm = reinterpret_cast<char*>(smem_i4);                                           \
    char* smA = sm; char* smB = sm + 16384;                                                \
    const int tid = threadIdx.x; const int lane = tid & 63; const int wid = tid >> 6;      \
    const int wr = (wid >> 1) * 64, wc = (wid & 1) * 64;                                   \
    const int r0 = blockIdx.x * 128, n0 = blockIdx.y * 128;                                \
    f32x4 acc[4][4] = {};                                                                  \
    const int srow = tid >> 3, sslot = tid & 7;                                            \
    for (int k0 = 0; k0 < E_DIM; k0 += 64) {                                               \
        __syncthreads();                                                                   \
        _Pragma("unroll") for (int p = 0; p < 4; ++p) {                                    \
            int row = p * 32 + srow;                                                       \
            int kc = k0 + ((sslot ^ (row & 7)) * 8);                                       \
            GLD_LDS16(&A[(size_t)(r0 + row) * E_DIM + kc], smA + p * 4096 + tid * 16);     \
            GLD_LDS16(&Bt[(size_t)(n0 + row) * E_DIM + kc], smB + p * 4096 + tid * 16);    \
        }                                                                                  \
        __syncthreads();                                                                   \
        _Pragma("unroll") for (int ks = 0; ks < 2; ++ks) {                                 \
            bf16x8 af[4], bfr[4];                                                          \
            _Pragma("unroll") for (int f = 0; f < 4; ++f) {                                \
                int ra = wr + f * 16 + (lane & 15);                                        \
                af[f] = *reinterpret_cast<bf16x8*>(smA + ra * 128 + (((ks * 4 + (lane >> 4)) ^ (ra & 7)) << 4)); \
                int rb = wc + f * 16 + (lane & 15);                                        \
                bfr[f] = *reinterpret_cast<bf16x8*>(smB + rb * 128 + (((ks * 4 + (lane >> 4)) ^ (rb & 7)) << 4)); \
            }                                                                              \
            _Pragma("unroll") for (int i = 0; i < 4; ++i)                                  \
                _Pragma("unroll") for (int j = 0; j < 4; ++j)                              \
                    acc[i][j] = __builtin_amdgcn_mfma_f32_16x16x32_bf16(af[i], bfr[j], acc[i][j], 0, 0, 0); \
        }                                                                                  \
    }

// QKV: A rows r = s*B+b. z selects W and output. Q,K stored [b][h][s][d] bf16;
// V stored transposed [b][h][d][s] bf16 (so PV's B-operand has contiguous k=j).
__global__ __launch_bounds__(256) void gemm_qkv(
        const unsigned short* __restrict__ A,
        const unsigned short* __restrict__ Wqt, const unsigned short* __restrict__ Wkt,
        const unsigned short* __restrict__ Wvt,
        unsigned short* __restrict__ Q, unsigned short* __restrict__ K,
        unsigned short* __restrict__ Vt) {
    const unsigned short* Bt = (blockIdx.z == 0) ? Wqt : (blockIdx.z == 1) ? Wkt : Wvt;
    GEMM_BODY
    unsigned short* O = (blockIdx.z == 0) ? Q : (blockIdx.z == 1) ? K : Vt;
    const int mode = blockIdx.z;
#pragma unroll
    for (int i = 0; i < 4; ++i)
#pragma unroll
    for (int j = 0; j < 4; ++j)
#pragma unroll
    for (int q = 0; q < 4; ++q) {
        int row = r0 + wr + i * 16 + (lane >> 4) * 4 + q;   // = s*2 + b
        int col = n0 + wc + j * 16 + (lane & 15);           // = h*64 + d
        int s = row >> 1, b = row & 1, h = col >> 6, d = col & 63;
        unsigned short v = f2bf(acc[i][j][q]);
        if (mode < 2) O[(((size_t)(b * H_DIM + h)) * S_DIM + s) * 64 + d] = v;
        else          O[(((size_t)(b * H_DIM + h)) * 64 + d) * S_DIM + s] = v;
    }
}

// out-proj: A = ctx bf16 [b*2048+s][1024]; out fp32 [(s*B+b)*E + e]
__global__ __launch_bounds__(256) void gemm_out(
        const unsigned short* __restrict__ A,
        const unsigned short* __restrict__ Bt, float* __restrict__ out) {
    GEMM_BODY
#pragma unroll
    for (int i = 0; i < 4; ++i)
#pragma unroll
    for (int j = 0; j < 4; ++j)
#pragma unroll
    for (int q = 0; q < 4; ++q) {
        int row = r0 + wr + i * 16 + (lane >> 4) * 4 + q;   // = b*2048 + s
        int b = row >> 11, s = row & 2047;
        int col = n0 + wc + j * 16 + (lane & 15);
        out[((size_t)(s * B_DIM + b)) * E_DIM + col] = acc[i][j][q];
    }
}

// ---------------- flash attention, bf16 MFMA ----------------
// 512 thr = 8 waves; wave owns 16 q-rows (block = 128 rows); KV tile 64.
// Q in regs; K/Vt staged via global_load_lds (linear dest, inverse-swizzled src);
// P via per-wave swizzled LDS round-trip. setprio(1) around MFMA clusters.
__global__ __launch_bounds__(512) void attn(
        const unsigned short* __restrict__ Q, const unsigned short* __restrict__ K,
        const unsigned short* __restrict__ Vt, unsigned short* __restrict__ ctx) {
    __shared__ int4 smem_i4[2048];
    char* sm = reinterpret_cast<char*>(smem_i4);
    char* smK = sm; char* smV = sm + 8192; char* smP = sm + 16384;
    const int tid = threadIdx.x, lane = tid & 63, wid = tid >> 6;
    const int bh = blockIdx.y;
    const int i0 = blockIdx.x * 128;
    const unsigned short* Qb = Q + (size_t)bh * S_DIM * 64;
    const unsigned short* Kb = K + (size_t)bh * S_DIM * 64;
    const unsigned short* Vb = Vt + (size_t)bh * 64 * S_DIM;
    char* smPw = smP + wid * 2048;   // 16 rows x 128B per wave

    bf16x8 qf[2];
#pragma unroll
    for (int ks = 0; ks < 2; ++ks) {
        int qrow = i0 + wid * 16 + (lane & 15);
        qf[ks] = *reinterpret_cast<const bf16x8*>(
            &Qb[(size_t)qrow * 64 + ks * 32 + (lane >> 4) * 8]);
    }

    f32x4 o[4] = {};
    float mrun[4], lrun[4];
#pragma unroll
    for (int q = 0; q < 4; ++q) { mrun[q] = -INFINITY; lrun[q] = 0.f; }

    const int srow = tid >> 3, sslot = tid & 7;   // 512 thr cover 64 rows x 8 slots

    for (int j0 = 0; j0 < S_DIM; j0 += 64) {
        __syncthreads();
        {
            int kc = (sslot ^ (srow & 7)) * 8;
            GLD_LDS16(&Kb[(size_t)(j0 + srow) * 64 + kc], smK + tid * 16);
            GLD_LDS16(&Vb[(size_t)srow * S_DIM + j0 + kc], smV + tid * 16);
        }
        __syncthreads();

        // QK^T: sv[jf][q] = S[qrow=(lane>>4)*4+q][j=jf*16+(lane&15)]
        f32x4 sv[4] = {};
        __builtin_amdgcn_s_setprio(1);
#pragma unroll
        for (int ks = 0; ks < 2; ++ks) {
            bf16x8 kf[4];
#pragma unroll
            for (int jf = 0; jf < 4; ++jf) {
                int r = jf * 16 + (lane & 15);
                kf[jf] = *reinterpret_cast<bf16x8*>(
                    smK + r * 128 + (((ks * 4 + (lane >> 4)) ^ (r & 7)) << 4));
            }
#pragma unroll
            for (int jf = 0; jf < 4; ++jf)
                sv[jf] = __builtin_amdgcn_mfma_f32_16x16x32_bf16(qf[ks], kf[jf], sv[jf], 0, 0, 0);
        }
        __builtin_amdgcn_s_setprio(0);

        // online softmax
#pragma unroll
        for (int jf = 0; jf < 4; ++jf) sv[jf] *= 0.125f;
        float ml[4];
#pragma unroll
        for (int q = 0; q < 4; ++q)
            ml[q] = fmaxf(fmaxf(sv[0][q], sv[1][q]), fmaxf(sv[2][q], sv[3][q]));
#pragma unroll
        for (int st = 1; st < 16; st <<= 1)
#pragma unroll
            for (int q = 0; q < 4; ++q)
                ml[q] = fmaxf(ml[q], __shfl_xor(ml[q], st));
#pragma unroll
        for (int q = 0; q < 4; ++q) {
            float mn = fmaxf(mrun[q], ml[q]);
            float al = __expf(mrun[q] - mn);
            mrun[q] = mn;
            lrun[q] *= al;
#pragma unroll
            for (int df = 0; df < 4; ++df) o[df][q] *= al;
        }
        float ls[4] = {0.f, 0.f, 0.f, 0.f};
#pragma unroll
        for (int jf = 0; jf < 4; ++jf)
#pragma unroll
            for (int q = 0; q < 4; ++q) {
                float p = __expf(sv[jf][q] - mrun[q]);
                ls[q] += p;
                int row = (lane >> 4) * 4 + q;
                int cb = (jf * 32 + (lane & 15) * 2) ^ ((row & 7) << 4);
                *reinterpret_cast<unsigned short*>(smPw + row * 128 + cb) = f2bf(p);
            }
#pragma unroll
        for (int st = 1; st < 16; st <<= 1)
#pragma unroll
            for (int q = 0; q < 4; ++q) ls[q] += __shfl_xor(ls[q], st);
#pragma unroll
        for (int q = 0; q < 4; ++q) lrun[q] += ls[q];

        // PV (A = P from per-wave LDS, B^T = Vt rows)
        __builtin_amdgcn_s_setprio(1);
#pragma unroll
        for (int ks = 0; ks < 2; ++ks) {
            bf16x8 pf, vf[4];
            {
                int r = lane & 15;
                pf = *reinterpret_cast<bf16x8*>(
                    smPw + r * 128 + (((ks * 4 + (lane >> 4)) ^ (r & 7)) << 4));
            }
#pragma unroll
            for (int df = 0; df < 4; ++df) {
                int r = df * 16 + (lane & 15);
                vf[df] = *reinterpret_cast<bf16x8*>(
                    smV + r * 128 + (((ks * 4 + (lane >> 4)) ^ (r & 7)) << 4));
            }
#pragma unroll
            for (int df = 0; df < 4; ++df)
                o[df] = __builtin_amdgcn_mfma_f32_16x16x32_bf16(pf, vf[df], o[df], 0, 0, 0);
        }
        __builtin_amdgcn_s_setprio(0);
    }

    // epilogue: ctx [b*2048+s][h*64+dv] bf16
    const int b = bh >> 4, h = bh & 15;
#pragma unroll
    for (int q = 0; q < 4; ++q) {
        float inv = 1.0f / lrun[q];
        int row = i0 + wid * 16 + (lane >> 4) * 4 + q;
#pragma unroll
        for (int df = 0; df < 4; ++df) {
            int col = h * 64 + df * 16 + (lane & 15);
            ctx[((size_t)(b * S_DIM + row)) * E_DIM + col] = f2bf(o[df][q] * inv);
        }
    }
}

extern "C" void kernel_launch(void* const* d_in, const int* in_sizes, int n_in,
                              void* d_out, int out_size, void* d_ws, size_t ws_size,
                              hipStream_t stream) {
    const float* X  = (const float*)d_in[0];
    const float* Wq = (const float*)d_in[1];
    const float* Wk = (const float*)d_in[2];
    const float* Wv = (const float*)d_in[3];
    const float* Wo = (const float*)d_in[4];
    float* out = (float*)d_out;

    char* ws = (char*)d_ws;
    const size_t MB = (size_t)1 << 20;
    unsigned short* Xb  = (unsigned short*)(ws);            //  8 MB
    unsigned short* Wqt = (unsigned short*)(ws +  8 * MB);  //  2 MB
    unsigned short* Wkt = (unsigned short*)(ws + 10 * MB);
    unsigned short* Wvt = (unsigned short*)(ws + 12 * MB);
    unsigned short* Wot = (unsigned short*)(ws + 14 * MB);
    unsigned short* Qb  = (unsigned short*)(ws + 16 * MB);  //  8 MB each
    unsigned short* Kb  = (unsigned short*)(ws + 24 * MB);
    unsigned short* Vt  = (unsigned short*)(ws + 32 * MB);
    unsigned short* ctx = (unsigned short*)(ws + 40 * MB);  // ends at 48 MB

    cast_x<<<dim3(2048), 256, 0, stream>>>(X, Xb);
    transpose_cast<<<dim3(16, 16, 4), 256, 0, stream>>>(Wq, Wk, Wv, Wo, Wqt, Wkt, Wvt, Wot);
    gemm_qkv<<<dim3(32, 8, 3), 256, 0, stream>>>(Xb, Wqt, Wkt, Wvt, Qb, Kb, Vt);
    attn<<<dim3(16, 32), 512, 0, stream>>>(Qb, Kb, Vt, ctx);
    gemm_out<<<dim3(32, 8), 256, 0, stream>>>(ctx, Wot, out);
}

// Round 8
// 247.175 us; speedup vs baseline: 1.0783x; 1.0286x over previous
//
#include <hip/hip_runtime.h>
#include <hip/hip_bf16.h>

#define S_DIM 2048
#define B_DIM 2
#define E_DIM 1024
#define H_DIM 16
#define M_ROWS 4096

typedef __attribute__((ext_vector_type(8))) short bf16x8;
typedef __attribute__((ext_vector_type(4))) float f32x4;

__device__ inline unsigned short f2bf(float x) {
    unsigned int b = __float_as_uint(x);
    return (unsigned short)((b + 0x7fffu + ((b >> 16) & 1u)) >> 16);  // RNE
}

// async global->LDS, 16B per lane; dest must be wave-uniform base + lane*16
#define GLD_LDS16(gsrc, ldst)                                                              \
    __builtin_amdgcn_global_load_lds((const __attribute__((address_space(1))) void*)(gsrc), \
                                     (__attribute__((address_space(3))) void*)(ldst), 16, 0, 0)

// ---------------- prep: cast X to bf16 ----------------
__global__ __launch_bounds__(256) void cast_x(const float* __restrict__ X,
                                              unsigned short* __restrict__ Xb) {
    int g = blockIdx.x * 256 + threadIdx.x;
    const float4* src = reinterpret_cast<const float4*>(X) + (size_t)g * 2;
    float4 v0 = src[0], v1 = src[1];
    union { unsigned short h[8]; int4 v; } u;
    u.h[0] = f2bf(v0.x); u.h[1] = f2bf(v0.y); u.h[2] = f2bf(v0.z); u.h[3] = f2bf(v0.w);
    u.h[4] = f2bf(v1.x); u.h[5] = f2bf(v1.y); u.h[6] = f2bf(v1.z); u.h[7] = f2bf(v1.w);
    *reinterpret_cast<int4*>(Xb + (size_t)g * 8) = u.v;
}

// ---------------- prep: Wt[n][k] = bf16(W[k][n]); Wq scaled by 1/8 (exact) ----
__global__ __launch_bounds__(256) void transpose_cast(
        const float* __restrict__ Wq, const float* __restrict__ Wk,
        const float* __restrict__ Wv, const float* __restrict__ Wo,
        unsigned short* __restrict__ Wqt, unsigned short* __restrict__ Wkt,
        unsigned short* __restrict__ Wvt, unsigned short* __restrict__ Wot) {
    const float* W = (blockIdx.z == 0) ? Wq : (blockIdx.z == 1) ? Wk
                   : (blockIdx.z == 2) ? Wv : Wo;
    unsigned short* Wt = (blockIdx.z == 0) ? Wqt : (blockIdx.z == 1) ? Wkt
                       : (blockIdx.z == 2) ? Wvt : Wot;
    const float scl = (blockIdx.z == 0) ? 0.125f : 1.0f;  // fold 1/sqrt(DK)=1/8 into Wq
    __shared__ float T[64][65];
    const int t = threadIdx.x;
    const int k0 = blockIdx.x * 64, n0 = blockIdx.y * 64;
#pragma unroll
    for (int p = 0; p < 4; ++p) {
        int r = p * 16 + (t >> 4), c4 = (t & 15) * 4;
        float4 v = *reinterpret_cast<const float4*>(&W[(size_t)(k0 + r) * E_DIM + n0 + c4]);
        T[r][c4] = v.x; T[r][c4 + 1] = v.y; T[r][c4 + 2] = v.z; T[r][c4 + 3] = v.w;
    }
    __syncthreads();
    const int nl = t >> 2, ks = (t & 3) * 16;
    union { unsigned short h[16]; int4 v[2]; } u;
#pragma unroll
    for (int i = 0; i < 16; ++i) u.h[i] = f2bf(T[ks + i][nl] * scl);
    int4* dst = reinterpret_cast<int4*>(&Wt[(size_t)(n0 + nl) * E_DIM + k0 + ks]);
    dst[0] = u.v[0]; dst[1] = u.v[1];
}

// ---------------- shared GEMM body: 128x128 tile, BK=64, 4 waves ----------------
// (unchanged from Round 7 — GEMM dbuf is a known neutral/regression, m99/m132)
#define GEMM_BODY                                                                          \
    __shared__ int4 smem_i4[2048];                                                         \
    char* sm = reinterpret_cast<char*>(smem_i4);                                           \
    char* smA = sm; char* smB = sm + 16384;                                                \
    const int tid = threadIdx.x; const int lane = tid & 63; const int wid = tid >> 6;      \
    const int wr = (wid >> 1) * 64, wc = (wid & 1) * 64;                                   \
    const int r0 = blockIdx.x * 128, n0 = blockIdx.y * 128;                                \
    f32x4 acc[4][4] = {};                                                                  \
    const int srow = tid >> 3, sslot = tid & 7;                                            \
    for (int k0 = 0; k0 < E_DIM; k0 += 64) {                                               \
        __syncthreads();                                                                   \
        _Pragma("unroll") for (int p = 0; p < 4; ++p) {                                    \
            int row = p * 32 + srow;                                                       \
            int kc = k0 + ((sslot ^ (row & 7)) * 8);                                       \
            GLD_LDS16(&A[(size_t)(r0 + row) * E_DIM + kc], smA + p * 4096 + tid * 16);     \
            GLD_LDS16(&Bt[(size_t)(n0 + row) * E_DIM + kc], smB + p * 4096 + tid * 16);    \
        }                                                                                  \
        __syncthreads();                                                                   \
        _Pragma("unroll") for (int ks = 0; ks < 2; ++ks) {                                 \
            bf16x8 af[4], bfr[4];                                                          \
            _Pragma("unroll") for (int f = 0; f < 4; ++f) {                                \
                int ra = wr + f * 16 + (lane & 15);                                        \
                af[f] = *reinterpret_cast<bf16x8*>(smA + ra * 128 + (((ks * 4 + (lane >> 4)) ^ (ra & 7)) << 4)); \
                int rb = wc + f * 16 + (lane & 15);                                        \
                bfr[f] = *reinterpret_cast<bf16x8*>(smB + rb * 128 + (((ks * 4 + (lane >> 4)) ^ (rb & 7)) << 4)); \
            }                                                                              \
            _Pragma("unroll") for (int i = 0; i < 4; ++i)                                  \
                _Pragma("unroll") for (int j = 0; j < 4; ++j)                              \
                    acc[i][j] = __builtin_amdgcn_mfma_f32_16x16x32_bf16(af[i], bfr[j], acc[i][j], 0, 0, 0); \
        }                                                                                  \
    }

__global__ __launch_bounds__(256) void gemm_qkv(
        const unsigned short* __restrict__ A,
        const unsigned short* __restrict__ Wqt, const unsigned short* __restrict__ Wkt,
        const unsigned short* __restrict__ Wvt,
        unsigned short* __restrict__ Q, unsigned short* __restrict__ K,
        unsigned short* __restrict__ Vt) {
    const unsigned short* Bt = (blockIdx.z == 0) ? Wqt : (blockIdx.z == 1) ? Wkt : Wvt;
    GEMM_BODY
    unsigned short* O = (blockIdx.z == 0) ? Q : (blockIdx.z == 1) ? K : Vt;
    const int mode = blockIdx.z;
#pragma unroll
    for (int i = 0; i < 4; ++i)
#pragma unroll
    for (int j = 0; j < 4; ++j)
#pragma unroll
    for (int q = 0; q < 4; ++q) {
        int row = r0 + wr + i * 16 + (lane >> 4) * 4 + q;   // = s*2 + b
        int col = n0 + wc + j * 16 + (lane & 15);           // = h*64 + d
        int s = row >> 1, b = row & 1, h = col >> 6, d = col & 63;
        unsigned short v = f2bf(acc[i][j][q]);
        if (mode < 2) O[(((size_t)(b * H_DIM + h)) * S_DIM + s) * 64 + d] = v;
        else          O[(((size_t)(b * H_DIM + h)) * 64 + d) * S_DIM + s] = v;
    }
}

__global__ __launch_bounds__(256) void gemm_out(
        const unsigned short* __restrict__ A,
        const unsigned short* __restrict__ Bt, float* __restrict__ out) {
    GEMM_BODY
#pragma unroll
    for (int i = 0; i < 4; ++i)
#pragma unroll
    for (int j = 0; j < 4; ++j)
#pragma unroll
    for (int q = 0; q < 4; ++q) {
        int row = r0 + wr + i * 16 + (lane >> 4) * 4 + q;   // = b*2048 + s
        int b = row >> 11, s = row & 2047;
        int col = n0 + wc + j * 16 + (lane & 15);
        out[((size_t)(s * B_DIM + b)) * E_DIM + col] = acc[i][j][q];
    }
}

// ---------------- flash attention, bf16 MFMA ----------------
// 512 thr = 8 waves x 16 q-rows; KV tile 64, DOUBLE-BUFFERED (issue-early /
// consume-after-barrier, T14/T3-lite). One barrier per iter. Q pre-scaled by
// 1/8 (folded into Wq). Defer-max THR=8 (T13). setprio around MFMA clusters.
__global__ __launch_bounds__(512) void attn(
        const unsigned short* __restrict__ Q, const unsigned short* __restrict__ K,
        const unsigned short* __restrict__ Vt, unsigned short* __restrict__ ctx) {
    __shared__ int4 smem_i4[3072];          // 48 KB
    char* sm = reinterpret_cast<char*>(smem_i4);
    char* smK = sm;                          // 2 bufs x 8 KB
    char* smV = sm + 16384;                  // 2 bufs x 8 KB
    char* smP = sm + 32768;                  // 8 waves x 2 KB
    const int tid = threadIdx.x, lane = tid & 63, wid = tid >> 6;
    const int bh = blockIdx.y;
    const int i0 = blockIdx.x * 128;
    const unsigned short* Qb = Q + (size_t)bh * S_DIM * 64;
    const unsigned short* Kb = K + (size_t)bh * S_DIM * 64;
    const unsigned short* Vb = Vt + (size_t)bh * 64 * S_DIM;
    char* smPw = smP + wid * 2048;           // 16 rows x 128B per wave

    bf16x8 qf[2];
#pragma unroll
    for (int ks = 0; ks < 2; ++ks) {
        int qrow = i0 + wid * 16 + (lane & 15);
        qf[ks] = *reinterpret_cast<const bf16x8*>(
            &Qb[(size_t)qrow * 64 + ks * 32 + (lane >> 4) * 8]);
    }

    f32x4 o[4] = {};
    float mrun[4], lrun[4];
#pragma unroll
    for (int q = 0; q < 4; ++q) { mrun[q] = -INFINITY; lrun[q] = 0.f; }

    const int srow = tid >> 3, sslot = tid & 7;     // 64 rows x 8 slots
    const int kc8 = (sslot ^ (srow & 7)) * 8;       // inverse-swizzled source col

    // prologue: stage tile 0 into buf 0
    GLD_LDS16(&Kb[(size_t)srow * 64 + kc8], smK + tid * 16);
    GLD_LDS16(&Vb[(size_t)srow * S_DIM + kc8], smV + tid * 16);

    int cur = 0;
    for (int t = 0; t < S_DIM / 64; ++t) {
        __syncthreads();   // implicit vmcnt(0): buf[cur] resident; prev reads done
        if (t + 1 < S_DIM / 64) {     // issue next tile into buf[cur^1] (hidden under compute)
            int j1 = (t + 1) * 64;
            GLD_LDS16(&Kb[(size_t)(j1 + srow) * 64 + kc8], smK + (cur ^ 1) * 8192 + tid * 16);
            GLD_LDS16(&Vb[(size_t)srow * S_DIM + j1 + kc8], smV + (cur ^ 1) * 8192 + tid * 16);
        }
        char* K_ = smK + cur * 8192;
        char* V_ = smV + cur * 8192;

        // QK^T (pre-scaled): sv[jf][q] = S[qrow=(lane>>4)*4+q][j=jf*16+(lane&15)]
        f32x4 sv[4] = {};
        __builtin_amdgcn_s_setprio(1);
#pragma unroll
        for (int ks = 0; ks < 2; ++ks) {
            bf16x8 kf[4];
#pragma unroll
            for (int jf = 0; jf < 4; ++jf) {
                int r = jf * 16 + (lane & 15);
                kf[jf] = *reinterpret_cast<bf16x8*>(
                    K_ + r * 128 + (((ks * 4 + (lane >> 4)) ^ (r & 7)) << 4));
            }
#pragma unroll
            for (int jf = 0; jf < 4; ++jf)
                sv[jf] = __builtin_amdgcn_mfma_f32_16x16x32_bf16(qf[ks], kf[jf], sv[jf], 0, 0, 0);
        }
        __builtin_amdgcn_s_setprio(0);

        // online softmax with defer-max (THR=8)
        float ml[4];
#pragma unroll
        for (int q = 0; q < 4; ++q)
            ml[q] = fmaxf(fmaxf(sv[0][q], sv[1][q]), fmaxf(sv[2][q], sv[3][q]));
#pragma unroll
        for (int st = 1; st < 16; st <<= 1)
#pragma unroll
            for (int q = 0; q < 4; ++q)
                ml[q] = fmaxf(ml[q], __shfl_xor(ml[q], st));
        int need = 0;
#pragma unroll
        for (int q = 0; q < 4; ++q) need |= (ml[q] > mrun[q] + 8.0f) ? 1 : 0;
        if (__any(need)) {
#pragma unroll
            for (int q = 0; q < 4; ++q) {
                float mn = fmaxf(mrun[q], ml[q]);
                float al = __expf(mrun[q] - mn);
                mrun[q] = mn;
                lrun[q] *= al;
#pragma unroll
                for (int df = 0; df < 4; ++df) o[df][q] *= al;
            }
        }
        float ls[4] = {0.f, 0.f, 0.f, 0.f};
#pragma unroll
        for (int jf = 0; jf < 4; ++jf)
#pragma unroll
            for (int q = 0; q < 4; ++q) {
                float p = __expf(sv[jf][q] - mrun[q]);   // bounded by e^8
                ls[q] += p;
                int row = (lane >> 4) * 4 + q;
                int cb = (jf * 32 + (lane & 15) * 2) ^ ((row & 7) << 4);
                *reinterpret_cast<unsigned short*>(smPw + row * 128 + cb) = f2bf(p);
            }
#pragma unroll
        for (int st = 1; st < 16; st <<= 1)
#pragma unroll
            for (int q = 0; q < 4; ++q) ls[q] += __shfl_xor(ls[q], st);
#pragma unroll
        for (int q = 0; q < 4; ++q) lrun[q] += ls[q];

        // PV (A = P from per-wave LDS, B^T = Vt rows)
        __builtin_amdgcn_s_setprio(1);
#pragma unroll
        for (int ks = 0; ks < 2; ++ks) {
            bf16x8 pf, vf[4];
            {
                int r = lane & 15;
                pf = *reinterpret_cast<bf16x8*>(
                    smPw + r * 128 + (((ks * 4 + (lane >> 4)) ^ (r & 7)) << 4));
            }
#pragma unroll
            for (int df = 0; df < 4; ++df) {
                int r = df * 16 + (lane & 15);
                vf[df] = *reinterpret_cast<bf16x8*>(
                    V_ + r * 128 + (((ks * 4 + (lane >> 4)) ^ (r & 7)) << 4));
            }
#pragma unroll
            for (int df = 0; df < 4; ++df)
                o[df] = __builtin_amdgcn_mfma_f32_16x16x32_bf16(pf, vf[df], o[df], 0, 0, 0);
        }
        __builtin_amdgcn_s_setprio(0);

        cur ^= 1;
    }

    // epilogue: ctx [b*2048+s][h*64+dv] bf16
    const int b = bh >> 4, h = bh & 15;
#pragma unroll
    for (int q = 0; q < 4; ++q) {
        float inv = 1.0f / lrun[q];
        int row = i0 + wid * 16 + (lane >> 4) * 4 + q;
#pragma unroll
        for (int df = 0; df < 4; ++df) {
            int col = h * 64 + df * 16 + (lane & 15);
            ctx[((size_t)(b * S_DIM + row)) * E_DIM + col] = f2bf(o[df][q] * inv);
        }
    }
}

extern "C" void kernel_launch(void* const* d_in, const int* in_sizes, int n_in,
                              void* d_out, int out_size, void* d_ws, size_t ws_size,
                              hipStream_t stream) {
    const float* X  = (const float*)d_in[0];
    const float* Wq = (const float*)d_in[1];
    const float* Wk = (const float*)d_in[2];
    const float* Wv = (const float*)d_in[3];
    const float* Wo = (const float*)d_in[4];
    float* out = (float*)d_out;

    char* ws = (char*)d_ws;
    const size_t MB = (size_t)1 << 20;
    unsigned short* Xb  = (unsigned short*)(ws);            //  8 MB
    unsigned short* Wqt = (unsigned short*)(ws +  8 * MB);  //  2 MB
    unsigned short* Wkt = (unsigned short*)(ws + 10 * MB);
    unsigned short* Wvt = (unsigned short*)(ws + 12 * MB);
    unsigned short* Wot = (unsigned short*)(ws + 14 * MB);
    unsigned short* Qb  = (unsigned short*)(ws + 16 * MB);  //  8 MB each
    unsigned short* Kb  = (unsigned short*)(ws + 24 * MB);
    unsigned short* Vt  = (unsigned short*)(ws + 32 * MB);
    unsigned short* ctx = (unsigned short*)(ws + 40 * MB);  // ends at 48 MB

    cast_x<<<dim3(2048), 256, 0, stream>>>(X, Xb);
    transpose_cast<<<dim3(16, 16, 4), 256, 0, stream>>>(Wq, Wk, Wv, Wo, Wqt, Wkt, Wvt, Wot);
    gemm_qkv<<<dim3(32, 8, 3), 256, 0, stream>>>(Xb, Wqt, Wkt, Wvt, Qb, Kb, Vt);
    attn<<<dim3(16, 32), 512, 0, stream>>>(Qb, Kb, Vt, ctx);
    gemm_out<<<dim3(32, 8), 256, 0, stream>>>(ctx, Wot, out);
}

// Round 9
// 214.430 us; speedup vs baseline: 1.2429x; 1.1527x over previous
//
#include <hip/hip_runtime.h>
#include <hip/hip_bf16.h>

#define S_DIM 2048
#define B_DIM 2
#define E_DIM 1024
#define H_DIM 16
#define M_ROWS 4096

typedef __attribute__((ext_vector_type(8))) short bf16x8;
typedef __attribute__((ext_vector_type(4))) float f32x4;

__device__ inline unsigned short f2bf(float x) {
    unsigned int b = __float_as_uint(x);
    return (unsigned short)((b + 0x7fffu + ((b >> 16) & 1u)) >> 16);  // RNE
}

// async global->LDS, 16B per lane; dest must be wave-uniform base + lane*16
#define GLD_LDS16(gsrc, ldst)                                                              \
    __builtin_amdgcn_global_load_lds((const __attribute__((address_space(1))) void*)(gsrc), \
                                     (__attribute__((address_space(3))) void*)(ldst), 16, 0, 0)

// ---------------- prep: cast X to bf16 ----------------
__global__ __launch_bounds__(256) void cast_x(const float* __restrict__ X,
                                              unsigned short* __restrict__ Xb) {
    int g = blockIdx.x * 256 + threadIdx.x;
    const float4* src = reinterpret_cast<const float4*>(X) + (size_t)g * 2;
    float4 v0 = src[0], v1 = src[1];
    union { unsigned short h[8]; int4 v; } u;
    u.h[0] = f2bf(v0.x); u.h[1] = f2bf(v0.y); u.h[2] = f2bf(v0.z); u.h[3] = f2bf(v0.w);
    u.h[4] = f2bf(v1.x); u.h[5] = f2bf(v1.y); u.h[6] = f2bf(v1.z); u.h[7] = f2bf(v1.w);
    *reinterpret_cast<int4*>(Xb + (size_t)g * 8) = u.v;
}

// ---------------- prep: Wt[n][k] = bf16(W[k][n]); Wq scaled by 1/8 (exact) ----
__global__ __launch_bounds__(256) void transpose_cast(
        const float* __restrict__ Wq, const float* __restrict__ Wk,
        const float* __restrict__ Wv, const float* __restrict__ Wo,
        unsigned short* __restrict__ Wqt, unsigned short* __restrict__ Wkt,
        unsigned short* __restrict__ Wvt, unsigned short* __restrict__ Wot) {
    const float* W = (blockIdx.z == 0) ? Wq : (blockIdx.z == 1) ? Wk
                   : (blockIdx.z == 2) ? Wv : Wo;
    unsigned short* Wt = (blockIdx.z == 0) ? Wqt : (blockIdx.z == 1) ? Wkt
                       : (blockIdx.z == 2) ? Wvt : Wot;
    const float scl = (blockIdx.z == 0) ? 0.125f : 1.0f;  // fold 1/sqrt(DK)=1/8 into Wq
    __shared__ float T[64][65];
    const int t = threadIdx.x;
    const int k0 = blockIdx.x * 64, n0 = blockIdx.y * 64;
#pragma unroll
    for (int p = 0; p < 4; ++p) {
        int r = p * 16 + (t >> 4), c4 = (t & 15) * 4;
        float4 v = *reinterpret_cast<const float4*>(&W[(size_t)(k0 + r) * E_DIM + n0 + c4]);
        T[r][c4] = v.x; T[r][c4 + 1] = v.y; T[r][c4 + 2] = v.z; T[r][c4 + 3] = v.w;
    }
    __syncthreads();
    const int nl = t >> 2, ks = (t & 3) * 16;
    union { unsigned short h[16]; int4 v[2]; } u;
#pragma unroll
    for (int i = 0; i < 16; ++i) u.h[i] = f2bf(T[ks + i][nl] * scl);
    int4* dst = reinterpret_cast<int4*>(&Wt[(size_t)(n0 + nl) * E_DIM + k0 + ks]);
    dst[0] = u.v[0]; dst[1] = u.v[1];
}

// ---------------- shared GEMM body: 128x128 tile, BK=64, 4 waves ----------------
#define GEMM_BODY                                                                          \
    __shared__ int4 smem_i4[2048];                                                         \
    char* sm = reinterpret_cast<char*>(smem_i4);                                           \
    char* smA = sm; char* smB = sm + 16384;                                                \
    const int tid = threadIdx.x; const int lane = tid & 63; const int wid = tid >> 6;      \
    const int wr = (wid >> 1) * 64, wc = (wid & 1) * 64;                                   \
    const int r0 = blockIdx.x * 128, n0 = blockIdx.y * 128;                                \
    f32x4 acc[4][4] = {};                                                                  \
    const int srow = tid >> 3, sslot = tid & 7;                                            \
    for (int k0 = 0; k0 < E_DIM; k0 += 64) {                                               \
        __syncthreads();                                                                   \
        _Pragma("unroll") for (int p = 0; p < 4; ++p) {                                    \
            int row = p * 32 + srow;                                                       \
            int kc = k0 + ((sslot ^ (row & 7)) * 8);                                       \
            GLD_LDS16(&A[(size_t)(r0 + row) * E_DIM + kc], smA + p * 4096 + tid * 16);     \
            GLD_LDS16(&Bt[(size_t)(n0 + row) * E_DIM + kc], smB + p * 4096 + tid * 16);    \
        }                                                                                  \
        __syncthreads();                                                                   \
        _Pragma("unroll") for (int ks = 0; ks < 2; ++ks) {                                 \
            bf16x8 af[4], bfr[4];                                                          \
            _Pragma("unroll") for (int f = 0; f < 4; ++f) {                                \
                int ra = wr + f * 16 + (lane & 15);                                        \
                af[f] = *reinterpret_cast<bf16x8*>(smA + ra * 128 + (((ks * 4 + (lane >> 4)) ^ (ra & 7)) << 4)); \
                int rb = wc + f * 16 + (lane & 15);                                        \
                bfr[f] = *reinterpret_cast<bf16x8*>(smB + rb * 128 + (((ks * 4 + (lane >> 4)) ^ (rb & 7)) << 4)); \
            }                                                                              \
            _Pragma("unroll") for (int i = 0; i < 4; ++i)                                  \
                _Pragma("unroll") for (int j = 0; j < 4; ++j)                              \
                    acc[i][j] = __builtin_amdgcn_mfma_f32_16x16x32_bf16(af[i], bfr[j], acc[i][j], 0, 0, 0); \
        }                                                                                  \
    }

__global__ __launch_bounds__(256) void gemm_qkv(
        const unsigned short* __restrict__ A,
        const unsigned short* __restrict__ Wqt, const unsigned short* __restrict__ Wkt,
        const unsigned short* __restrict__ Wvt,
        unsigned short* __restrict__ Q, unsigned short* __restrict__ K,
        unsigned short* __restrict__ Vt) {
    const unsigned short* Bt = (blockIdx.z == 0) ? Wqt : (blockIdx.z == 1) ? Wkt : Wvt;
    GEMM_BODY
    unsigned short* O = (blockIdx.z == 0) ? Q : (blockIdx.z == 1) ? K : Vt;
    const int mode = blockIdx.z;
#pragma unroll
    for (int i = 0; i < 4; ++i)
#pragma unroll
    for (int j = 0; j < 4; ++j)
#pragma unroll
    for (int q = 0; q < 4; ++q) {
        int row = r0 + wr + i * 16 + (lane >> 4) * 4 + q;   // = s*2 + b
        int col = n0 + wc + j * 16 + (lane & 15);           // = h*64 + d
        int s = row >> 1, b = row & 1, h = col >> 6, d = col & 63;
        unsigned short v = f2bf(acc[i][j][q]);
        if (mode < 2) O[(((size_t)(b * H_DIM + h)) * S_DIM + s) * 64 + d] = v;
        else          O[(((size_t)(b * H_DIM + h)) * 64 + d) * S_DIM + s] = v;
    }
}

__global__ __launch_bounds__(256) void gemm_out(
        const unsigned short* __restrict__ A,
        const unsigned short* __restrict__ Bt, float* __restrict__ out) {
    GEMM_BODY
#pragma unroll
    for (int i = 0; i < 4; ++i)
#pragma unroll
    for (int j = 0; j < 4; ++j)
#pragma unroll
    for (int q = 0; q < 4; ++q) {
        int row = r0 + wr + i * 16 + (lane >> 4) * 4 + q;   // = b*2048 + s
        int b = row >> 11, s = row & 2047;
        int col = n0 + wc + j * 16 + (lane & 15);
        out[((size_t)(s * B_DIM + b)) * E_DIM + col] = acc[i][j][q];
    }
}

// ---------------- flash attention, bf16 MFMA, SWAPPED QK^T (T12-style) -------
// 512 thr = 8 waves x 16 q-rows; KV tile 64, double-buffered K/V.
// QK^T computed as S^T = mfma(K, Q): lane owns q-row (lane&15), 16 j's in regs
// -> softmax reduction = in-register + 2 shfl_xor (was 32 shfls).
// P packed to bf16 pairs, 4x8B swizzled LDS writes; PV unchanged (A=P, B=Vt).
__global__ __launch_bounds__(512) void attn(
        const unsigned short* __restrict__ Q, const unsigned short* __restrict__ K,
        const unsigned short* __restrict__ Vt, unsigned short* __restrict__ ctx) {
    __shared__ int4 smem_i4[3072];          // 48 KB
    char* sm = reinterpret_cast<char*>(smem_i4);
    char* smK = sm;                          // 2 bufs x 8 KB
    char* smV = sm + 16384;                  // 2 bufs x 8 KB
    char* smP = sm + 32768;                  // 8 waves x 2 KB
    const int tid = threadIdx.x, lane = tid & 63, wid = tid >> 6;
    const int bh = blockIdx.y;
    const int i0 = blockIdx.x * 128;
    const unsigned short* Qb = Q + (size_t)bh * S_DIM * 64;
    const unsigned short* Kb = K + (size_t)bh * S_DIM * 64;
    const unsigned short* Vb = Vt + (size_t)bh * 64 * S_DIM;
    char* smPw = smP + wid * 2048;           // 16 rows x 128B per wave

    bf16x8 qf[2];                            // B-operand: n=qrow=lane&15, k slots
#pragma unroll
    for (int ks = 0; ks < 2; ++ks) {
        int qrow = i0 + wid * 16 + (lane & 15);
        qf[ks] = *reinterpret_cast<const bf16x8*>(
            &Qb[(size_t)qrow * 64 + ks * 32 + (lane >> 4) * 8]);
    }

    f32x4 o[4] = {};
    float mrun = -INFINITY, lrun = 0.f;      // per-lane scalars (qrow = lane&15)

    const int srow = tid >> 3, sslot = tid & 7;     // 64 rows x 8 slots
    const int kc8 = (sslot ^ (srow & 7)) * 8;       // inverse-swizzled source col
    const int prow = lane & 15;
    const int xl = (lane & 48) | ((lane >> 4) * 4); // transpose-shfl base

    // prologue: stage tile 0 into buf 0
    GLD_LDS16(&Kb[(size_t)srow * 64 + kc8], smK + tid * 16);
    GLD_LDS16(&Vb[(size_t)srow * S_DIM + kc8], smV + tid * 16);

    int cur = 0;
    for (int t = 0; t < S_DIM / 64; ++t) {
        __syncthreads();   // implicit vmcnt(0): buf[cur] resident; prev reads done
        if (t + 1 < S_DIM / 64) {     // issue next tile into buf[cur^1]
            int j1 = (t + 1) * 64;
            GLD_LDS16(&Kb[(size_t)(j1 + srow) * 64 + kc8], smK + (cur ^ 1) * 8192 + tid * 16);
            GLD_LDS16(&Vb[(size_t)srow * S_DIM + j1 + kc8], smV + (cur ^ 1) * 8192 + tid * 16);
        }
        char* K_ = smK + cur * 8192;
        char* V_ = smV + cur * 8192;

        // swapped QK^T: sv[jf][r] = S[qrow=lane&15][j = jf*16 + (lane>>4)*4 + r]
        f32x4 sv[4] = {};
        __builtin_amdgcn_s_setprio(1);
#pragma unroll
        for (int ks = 0; ks < 2; ++ks) {
            bf16x8 kf[4];
#pragma unroll
            for (int jf = 0; jf < 4; ++jf) {
                int r = jf * 16 + (lane & 15);
                kf[jf] = *reinterpret_cast<bf16x8*>(
                    K_ + r * 128 + (((ks * 4 + (lane >> 4)) ^ (r & 7)) << 4));
            }
#pragma unroll
            for (int jf = 0; jf < 4; ++jf)
                sv[jf] = __builtin_amdgcn_mfma_f32_16x16x32_bf16(kf[jf], qf[ks], sv[jf], 0, 0, 0);
        }
        __builtin_amdgcn_s_setprio(0);

        // softmax: lane-local row; in-register max/sum + 2 shfls
        float ml = sv[0][0];
#pragma unroll
        for (int jf = 0; jf < 4; ++jf)
#pragma unroll
            for (int r = 0; r < 4; ++r) ml = fmaxf(ml, sv[jf][r]);
        ml = fmaxf(ml, __shfl_xor(ml, 16));
        ml = fmaxf(ml, __shfl_xor(ml, 32));
        if (__any(ml > mrun + 8.0f)) {        // defer-max THR=8
            float mn = fmaxf(mrun, ml);
            float al = __expf(mrun - mn);
            mrun = mn; lrun *= al;
            float al4[4];
#pragma unroll
            for (int q = 0; q < 4; ++q) al4[q] = __shfl(al, xl + q);
#pragma unroll
            for (int df = 0; df < 4; ++df)
#pragma unroll
                for (int q = 0; q < 4; ++q) o[df][q] *= al4[q];
        }
        float ls = 0.f;
        char* pbase = smPw + prow * 128;
#pragma unroll
        for (int jf = 0; jf < 4; ++jf) {
            float p0 = __expf(sv[jf][0] - mrun), p1 = __expf(sv[jf][1] - mrun);
            float p2 = __expf(sv[jf][2] - mrun), p3 = __expf(sv[jf][3] - mrun);
            ls += (p0 + p1) + (p2 + p3);
            unsigned int w0 = ((unsigned int)f2bf(p1) << 16) | f2bf(p0);
            unsigned int w1 = ((unsigned int)f2bf(p3) << 16) | f2bf(p2);
            int cb = jf * 32 + (lane >> 4) * 8;                    // byte col of j-run
            int byte = (((cb >> 4) ^ (prow & 7)) << 4) | (cb & 15); // swizzled
            uint2 w; w.x = w0; w.y = w1;
            *reinterpret_cast<uint2*>(pbase + byte) = w;
        }
        ls += __shfl_xor(ls, 16);
        ls += __shfl_xor(ls, 32);
        lrun += ls;

        // PV (A = P from per-wave LDS, B^T = Vt rows)
        __builtin_amdgcn_s_setprio(1);
#pragma unroll
        for (int ks = 0; ks < 2; ++ks) {
            bf16x8 pf, vf[4];
            {
                int r = lane & 15;
                pf = *reinterpret_cast<bf16x8*>(
                    smPw + r * 128 + (((ks * 4 + (lane >> 4)) ^ (r & 7)) << 4));
            }
#pragma unroll
            for (int df = 0; df < 4; ++df) {
                int r = df * 16 + (lane & 15);
                vf[df] = *reinterpret_cast<bf16x8*>(
                    V_ + r * 128 + (((ks * 4 + (lane >> 4)) ^ (r & 7)) << 4));
            }
#pragma unroll
            for (int df = 0; df < 4; ++df)
                o[df] = __builtin_amdgcn_mfma_f32_16x16x32_bf16(pf, vf[df], o[df], 0, 0, 0);
        }
        __builtin_amdgcn_s_setprio(0);

        cur ^= 1;
    }

    // epilogue: transpose lrun to o-row layout, store ctx [b*2048+s][h*64+dv]
    float linv = 1.0f / lrun;
    float linv4[4];
#pragma unroll
    for (int q = 0; q < 4; ++q) linv4[q] = __shfl(linv, xl + q);
    const int b = bh >> 4, h = bh & 15;
#pragma unroll
    for (int q = 0; q < 4; ++q) {
        int row = i0 + wid * 16 + (lane >> 4) * 4 + q;
#pragma unroll
        for (int df = 0; df < 4; ++df) {
            int col = h * 64 + df * 16 + (lane & 15);
            ctx[((size_t)(b * S_DIM + row)) * E_DIM + col] = f2bf(o[df][q] * linv4[q]);
        }
    }
}

extern "C" void kernel_launch(void* const* d_in, const int* in_sizes, int n_in,
                              void* d_out, int out_size, void* d_ws, size_t ws_size,
                              hipStream_t stream) {
    const float* X  = (const float*)d_in[0];
    const float* Wq = (const float*)d_in[1];
    const float* Wk = (const float*)d_in[2];
    const float* Wv = (const float*)d_in[3];
    const float* Wo = (const float*)d_in[4];
    float* out = (float*)d_out;

    char* ws = (char*)d_ws;
    const size_t MB = (size_t)1 << 20;
    unsigned short* Xb  = (unsigned short*)(ws);            //  8 MB
    unsigned short* Wqt = (unsigned short*)(ws +  8 * MB);  //  2 MB
    unsigned short* Wkt = (unsigned short*)(ws + 10 * MB);
    unsigned short* Wvt = (unsigned short*)(ws + 12 * MB);
    unsigned short* Wot = (unsigned short*)(ws + 14 * MB);
    unsigned short* Qb  = (unsigned short*)(ws + 16 * MB);  //  8 MB each
    unsigned short* Kb  = (unsigned short*)(ws + 24 * MB);
    unsigned short* Vt  = (unsigned short*)(ws + 32 * MB);
    unsigned short* ctx = (unsigned short*)(ws + 40 * MB);  // ends at 48 MB

    cast_x<<<dim3(2048), 256, 0, stream>>>(X, Xb);
    transpose_cast<<<dim3(16, 16, 4), 256, 0, stream>>>(Wq, Wk, Wv, Wo, Wqt, Wkt, Wvt, Wot);
    gemm_qkv<<<dim3(32, 8, 3), 256, 0, stream>>>(Xb, Wqt, Wkt, Wvt, Qb, Kb, Vt);
    attn<<<dim3(16, 32), 512, 0, stream>>>(Qb, Kb, Vt, ctx);
    gemm_out<<<dim3(32, 8), 256, 0, stream>>>(ctx, Wot, out);
}

// Round 10
// 197.242 us; speedup vs baseline: 1.3513x; 1.0871x over previous
//
#include <hip/hip_runtime.h>
#include <hip/hip_bf16.h>

#define S_DIM 2048
#define B_DIM 2
#define E_DIM 1024
#define H_DIM 16
#define M_ROWS 4096

typedef __attribute__((ext_vector_type(8))) short bf16x8;
typedef __attribute__((ext_vector_type(4))) float f32x4;

__device__ inline unsigned short f2bf(float x) {
    unsigned int b = __float_as_uint(x);
    return (unsigned short)((b + 0x7fffu + ((b >> 16) & 1u)) >> 16);  // RNE
}
__device__ inline unsigned short f2bfh(float x) {   // HW cvt (pairs fuse to cvt_pk)
    __hip_bfloat16 h = __float2bfloat16(x);
    return *reinterpret_cast<unsigned short*>(&h);
}

// async global->LDS, 16B per lane; dest must be wave-uniform base + lane*16
#define GLD_LDS16(gsrc, ldst)                                                              \
    __builtin_amdgcn_global_load_lds((const __attribute__((address_space(1))) void*)(gsrc), \
                                     (__attribute__((address_space(3))) void*)(ldst), 16, 0, 0)

// ---------------- fused prep: blocks 0-2047 cast X; 2048-3071 transpose W ----
__global__ __launch_bounds__(256) void prep(
        const float* __restrict__ X,
        const float* __restrict__ Wq, const float* __restrict__ Wk,
        const float* __restrict__ Wv, const float* __restrict__ Wo,
        unsigned short* __restrict__ Xb,
        unsigned short* __restrict__ Wqt, unsigned short* __restrict__ Wkt,
        unsigned short* __restrict__ Wvt, unsigned short* __restrict__ Wot) {
    __shared__ float T[64][65];
    const int t = threadIdx.x;
    if (blockIdx.x < 2048) {
        int g = blockIdx.x * 256 + t;
        const float4* src = reinterpret_cast<const float4*>(X) + (size_t)g * 2;
        float4 v0 = src[0], v1 = src[1];
        union { unsigned short h[8]; int4 v; } u;
        u.h[0] = f2bf(v0.x); u.h[1] = f2bf(v0.y); u.h[2] = f2bf(v0.z); u.h[3] = f2bf(v0.w);
        u.h[4] = f2bf(v1.x); u.h[5] = f2bf(v1.y); u.h[6] = f2bf(v1.z); u.h[7] = f2bf(v1.w);
        *reinterpret_cast<int4*>(Xb + (size_t)g * 8) = u.v;
        return;
    }
    int f = blockIdx.x - 2048;
    int z = f >> 8, rem = f & 255;
    const float* W = (z == 0) ? Wq : (z == 1) ? Wk : (z == 2) ? Wv : Wo;
    unsigned short* Wt = (z == 0) ? Wqt : (z == 1) ? Wkt : (z == 2) ? Wvt : Wot;
    const float scl = (z == 0) ? 0.125f : 1.0f;   // fold 1/sqrt(DK)=1/8 into Wq
    const int k0 = (rem >> 4) * 64, n0 = (rem & 15) * 64;
#pragma unroll
    for (int p = 0; p < 4; ++p) {
        int r = p * 16 + (t >> 4), c4 = (t & 15) * 4;
        float4 v = *reinterpret_cast<const float4*>(&W[(size_t)(k0 + r) * E_DIM + n0 + c4]);
        T[r][c4] = v.x; T[r][c4 + 1] = v.y; T[r][c4 + 2] = v.z; T[r][c4 + 3] = v.w;
    }
    __syncthreads();
    const int nl = t >> 2, ks = (t & 3) * 16;
    union { unsigned short h[16]; int4 v[2]; } u;
#pragma unroll
    for (int i = 0; i < 16; ++i) u.h[i] = f2bf(T[ks + i][nl] * scl);
    int4* dst = reinterpret_cast<int4*>(&Wt[(size_t)(n0 + nl) * E_DIM + k0 + ks]);
    dst[0] = u.v[0]; dst[1] = u.v[1];
}

// ---------------- shared GEMM body: 128x128 tile, BK=64, 4 waves ----------------
// AROWE maps LDS tile-row `row` (0..127) to the global A row index.
#define GEMM_BODY(AROWE)                                                                   \
    __shared__ int4 smem_i4[2048];                                                         \
    char* sm = reinterpret_cast<char*>(smem_i4);                                           \
    char* smA = sm; char* smB = sm + 16384;                                                \
    const int tid = threadIdx.x; const int lane = tid & 63; const int wid = tid >> 6;      \
    const int wr = (wid >> 1) * 64, wc = (wid & 1) * 64;                                   \
    const int n0 = blockIdx.y * 128;                                                       \
    f32x4 acc[4][4] = {};                                                                  \
    const int srow = tid >> 3, sslot = tid & 7;                                            \
    for (int k0 = 0; k0 < E_DIM; k0 += 64) {                                               \
        __syncthreads();                                                                   \
        _Pragma("unroll") for (int p = 0; p < 4; ++p) {                                    \
            int row = p * 32 + srow;                                                       \
            int arow = (AROWE);                                                            \
            int kc = k0 + ((sslot ^ (row & 7)) * 8);                                       \
            GLD_LDS16(&A[(size_t)arow * E_DIM + kc], smA + p * 4096 + tid * 16);           \
            GLD_LDS16(&Bt[(size_t)(n0 + row) * E_DIM + kc], smB + p * 4096 + tid * 16);    \
        }                                                                                  \
        __syncthreads();                                                                   \
        _Pragma("unroll") for (int ks = 0; ks < 2; ++ks) {                                 \
            bf16x8 af[4], bfr[4];                                                          \
            _Pragma("unroll") for (int f = 0; f < 4; ++f) {                                \
                int ra = wr + f * 16 + (lane & 15);                                        \
                af[f] = *reinterpret_cast<bf16x8*>(smA + ra * 128 + (((ks * 4 + (lane >> 4)) ^ (ra & 7)) << 4)); \
                int rb = wc + f * 16 + (lane & 15);                                        \
                bfr[f] = *reinterpret_cast<bf16x8*>(smB + rb * 128 + (((ks * 4 + (lane >> 4)) ^ (rb & 7)) << 4)); \
            }                                                                              \
            _Pragma("unroll") for (int i = 0; i < 4; ++i)                                  \
                _Pragma("unroll") for (int j = 0; j < 4; ++j)                              \
                    acc[i][j] = __builtin_amdgcn_mfma_f32_16x16x32_bf16(af[i], bfr[j], acc[i][j], 0, 0, 0); \
        }                                                                                  \
    }

// QKV with b-major tile rows: tile row u -> X row (sB+(u&63))*2 + (u>>6), so
// (s,b) = (sB+(u&63), u>>6). Epilogue: bf16 LDS transpose buffer (XOR-swizzled)
// -> 8 coalesced dwordx4 stores/thread. Q,K: [b][h][s][d]; V: [b][h][d][s].
__global__ __launch_bounds__(256) void gemm_qkv(
        const unsigned short* __restrict__ A,
        const unsigned short* __restrict__ Wqt, const unsigned short* __restrict__ Wkt,
        const unsigned short* __restrict__ Wvt,
        unsigned short* __restrict__ Q, unsigned short* __restrict__ K,
        unsigned short* __restrict__ Vt) {
    const unsigned short* Bt = (blockIdx.z == 0) ? Wqt : (blockIdx.z == 1) ? Wkt : Wvt;
    GEMM_BODY(((int)blockIdx.x * 64 + (row & 63)) * 2 + (row >> 6))
    const int sB = blockIdx.x * 64;
    const int mode = blockIdx.z;
    unsigned short* O = (mode == 0) ? Q : (mode == 1) ? K : Vt;
    __syncthreads();   // last MFMA reads done before smem overwrite
    if (mode < 2) {    // L[u][n]: addr = u*256 + ((n*2) ^ ((u&15)<<4))
#pragma unroll
        for (int i = 0; i < 4; ++i)
#pragma unroll
        for (int q = 0; q < 4; ++q) {
            int u = wr + i * 16 + (lane >> 4) * 4 + q;
            int ub = u * 256, ux = (u & 15) << 4;
#pragma unroll
            for (int j = 0; j < 4; ++j) {
                int n = wc + j * 16 + (lane & 15);
                *reinterpret_cast<unsigned short*>(sm + ub + ((n * 2) ^ ux)) = f2bfh(acc[i][j][q]);
            }
        }
    } else {           // Lt[n][u]: addr = n*256 + ((u*2) ^ ((n&15)<<4))
#pragma unroll
        for (int j = 0; j < 4; ++j) {
            int n = wc + j * 16 + (lane & 15);
            int nb = n * 256, nx = (n & 15) << 4;
#pragma unroll
            for (int i = 0; i < 4; ++i)
#pragma unroll
            for (int q = 0; q < 4; ++q) {
                int u = wr + i * 16 + (lane >> 4) * 4 + q;
                *reinterpret_cast<unsigned short*>(sm + nb + ((u * 2) ^ nx)) = f2bfh(acc[i][j][q]);
            }
        }
    }
    __syncthreads();
    const int rr = tid >> 4, cb16 = (tid & 15) * 16;
#pragma unroll
    for (int pass = 0; pass < 8; ++pass) {
        if (mode < 2) {
            int u = pass * 16 + rr;
            int4 v = *reinterpret_cast<int4*>(sm + u * 256 + (cb16 ^ ((u & 15) << 4)));
            int cg = n0 + (cb16 >> 1);
            int h = cg >> 6, d = cg & 63;
            int s = sB + (u & 63), b = u >> 6;
            *reinterpret_cast<int4*>(&O[(((size_t)(b * 16 + h)) * 2048 + s) * 64 + d]) = v;
        } else {
            int n = pass * 16 + rr;
            int4 v = *reinterpret_cast<int4*>(sm + n * 256 + (cb16 ^ ((n & 15) << 4)));
            int cg = n0 + n;
            int h = cg >> 6, d = cg & 63;
            int u0 = cb16 >> 1;
            int b = u0 >> 6, s = sB + (u0 & 63);
            *reinterpret_cast<int4*>(&O[(((size_t)(b * 16 + h)) * 64 + d) * 2048 + s]) = v;
        }
    }
}

// out-proj: A = ctx bf16 [b*2048+s][1024]; out fp32 [(s*B+b)*E + e]
__global__ __launch_bounds__(256) void gemm_out(
        const unsigned short* __restrict__ A,
        const unsigned short* __restrict__ Bt, float* __restrict__ out) {
    GEMM_BODY((int)blockIdx.x * 128 + row)
    const int r0 = blockIdx.x * 128;
#pragma unroll
    for (int i = 0; i < 4; ++i)
#pragma unroll
    for (int j = 0; j < 4; ++j)
#pragma unroll
    for (int q = 0; q < 4; ++q) {
        int row = r0 + wr + i * 16 + (lane >> 4) * 4 + q;   // = b*2048 + s
        int b = row >> 11, s = row & 2047;
        int col = n0 + wc + j * 16 + (lane & 15);
        out[((size_t)(s * B_DIM + b)) * E_DIM + col] = acc[i][j][q];
    }
}

// ---------------- flash attention, bf16 MFMA, swapped QK^T ----------------
__global__ __launch_bounds__(512) void attn(
        const unsigned short* __restrict__ Q, const unsigned short* __restrict__ K,
        const unsigned short* __restrict__ Vt, unsigned short* __restrict__ ctx) {
    __shared__ int4 smem_i4[3072];          // 48 KB
    char* sm = reinterpret_cast<char*>(smem_i4);
    char* smK = sm;                          // 2 bufs x 8 KB
    char* smV = sm + 16384;                  // 2 bufs x 8 KB
    char* smP = sm + 32768;                  // 8 waves x 2 KB
    const int tid = threadIdx.x, lane = tid & 63, wid = tid >> 6;
    const int bh = blockIdx.y;
    const int i0 = blockIdx.x * 128;
    const unsigned short* Qb = Q + (size_t)bh * S_DIM * 64;
    const unsigned short* Kb = K + (size_t)bh * S_DIM * 64;
    const unsigned short* Vb = Vt + (size_t)bh * 64 * S_DIM;
    char* smPw = smP + wid * 2048;           // 16 rows x 128B per wave

    bf16x8 qf[2];                            // B-operand: n=qrow=lane&15
#pragma unroll
    for (int ks = 0; ks < 2; ++ks) {
        int qrow = i0 + wid * 16 + (lane & 15);
        qf[ks] = *reinterpret_cast<const bf16x8*>(
            &Qb[(size_t)qrow * 64 + ks * 32 + (lane >> 4) * 8]);
    }

    f32x4 o[4] = {};
    float mrun = -INFINITY, lrun = 0.f;      // per-lane scalars (qrow = lane&15)

    const int srow = tid >> 3, sslot = tid & 7;
    const int kc8 = (sslot ^ (srow & 7)) * 8;
    const int prow = lane & 15;
    const int xl = (lane & 48) | ((lane >> 4) * 4); // transpose-shfl base

    GLD_LDS16(&Kb[(size_t)srow * 64 + kc8], smK + tid * 16);
    GLD_LDS16(&Vb[(size_t)srow * S_DIM + kc8], smV + tid * 16);

#pragma unroll 2
    for (int t = 0; t < S_DIM / 64; ++t) {
        __syncthreads();
        if (t + 1 < S_DIM / 64) {
            int j1 = (t + 1) * 64;
            GLD_LDS16(&Kb[(size_t)(j1 + srow) * 64 + kc8], smK + ((t & 1) ^ 1) * 8192 + tid * 16);
            GLD_LDS16(&Vb[(size_t)srow * S_DIM + j1 + kc8], smV + ((t & 1) ^ 1) * 8192 + tid * 16);
        }
        char* K_ = smK + (t & 1) * 8192;
        char* V_ = smV + (t & 1) * 8192;

        // swapped QK^T: sv[jf][r] = S[qrow=lane&15][j = jf*16 + (lane>>4)*4 + r]
        f32x4 sv[4] = {};
        __builtin_amdgcn_s_setprio(1);
#pragma unroll
        for (int ks = 0; ks < 2; ++ks) {
            bf16x8 kf[4];
#pragma unroll
            for (int jf = 0; jf < 4; ++jf) {
                int r = jf * 16 + (lane & 15);
                kf[jf] = *reinterpret_cast<bf16x8*>(
                    K_ + r * 128 + (((ks * 4 + (lane >> 4)) ^ (r & 7)) << 4));
            }
#pragma unroll
            for (int jf = 0; jf < 4; ++jf)
                sv[jf] = __builtin_amdgcn_mfma_f32_16x16x32_bf16(kf[jf], qf[ks], sv[jf], 0, 0, 0);
        }
        __builtin_amdgcn_s_setprio(0);

        // softmax: lane-local row; max3-friendly reduction + 2 shfls
        float m0 = fmaxf(fmaxf(sv[0][0], sv[0][1]), sv[0][2]);
        float m1 = fmaxf(fmaxf(sv[0][3], sv[1][0]), sv[1][1]);
        float m2 = fmaxf(fmaxf(sv[1][2], sv[1][3]), sv[2][0]);
        float m3 = fmaxf(fmaxf(sv[2][1], sv[2][2]), sv[2][3]);
        float m4 = fmaxf(fmaxf(sv[3][0], sv[3][1]), sv[3][2]);
        float ml = fmaxf(fmaxf(m0, m1), m2);
        ml = fmaxf(fmaxf(ml, m3), m4);
        ml = fmaxf(ml, sv[3][3]);
        ml = fmaxf(ml, __shfl_xor(ml, 16));
        ml = fmaxf(ml, __shfl_xor(ml, 32));
        if (__any(ml > mrun + 8.0f)) {        // defer-max THR=8
            float mn = fmaxf(mrun, ml);
            float al = __expf(mrun - mn);
            mrun = mn; lrun *= al;
            float al4[4];
#pragma unroll
            for (int q = 0; q < 4; ++q) al4[q] = __shfl(al, xl + q);
#pragma unroll
            for (int df = 0; df < 4; ++df)
#pragma unroll
                for (int q = 0; q < 4; ++q) o[df][q] *= al4[q];
        }
        float ls = 0.f;
        char* pbase = smPw + prow * 128;
#pragma unroll
        for (int jf = 0; jf < 4; ++jf) {
            float p0 = __expf(sv[jf][0] - mrun), p1 = __expf(sv[jf][1] - mrun);
            float p2 = __expf(sv[jf][2] - mrun), p3 = __expf(sv[jf][3] - mrun);
            ls += (p0 + p1) + (p2 + p3);
            unsigned int w0 = ((unsigned int)f2bfh(p1) << 16) | f2bfh(p0);
            unsigned int w1 = ((unsigned int)f2bfh(p3) << 16) | f2bfh(p2);
            int cb = jf * 32 + (lane >> 4) * 8;
            int byte = (((cb >> 4) ^ (prow & 7)) << 4) | (cb & 15);
            uint2 w; w.x = w0; w.y = w1;
            *reinterpret_cast<uint2*>(pbase + byte) = w;
        }
        ls += __shfl_xor(ls, 16);
        ls += __shfl_xor(ls, 32);
        lrun += ls;

        // PV (A = P from per-wave LDS, B^T = Vt rows)
        __builtin_amdgcn_s_setprio(1);
#pragma unroll
        for (int ks = 0; ks < 2; ++ks) {
            bf16x8 pf, vf[4];
            {
                int r = lane & 15;
                pf = *reinterpret_cast<bf16x8*>(
                    smPw + r * 128 + (((ks * 4 + (lane >> 4)) ^ (r & 7)) << 4));
            }
#pragma unroll
            for (int df = 0; df < 4; ++df) {
                int r = df * 16 + (lane & 15);
                vf[df] = *reinterpret_cast<bf16x8*>(
                    V_ + r * 128 + (((ks * 4 + (lane >> 4)) ^ (r & 7)) << 4));
            }
#pragma unroll
            for (int df = 0; df < 4; ++df)
                o[df] = __builtin_amdgcn_mfma_f32_16x16x32_bf16(pf, vf[df], o[df], 0, 0, 0);
        }
        __builtin_amdgcn_s_setprio(0);
    }

    // epilogue: transpose lrun to o-row layout, store ctx [b*2048+s][h*64+dv]
    float linv = 1.0f / lrun;
    float linv4[4];
#pragma unroll
    for (int q = 0; q < 4; ++q) linv4[q] = __shfl(linv, xl + q);
    const int b = bh >> 4, h = bh & 15;
#pragma unroll
    for (int q = 0; q < 4; ++q) {
        int row = i0 + wid * 16 + (lane >> 4) * 4 + q;
#pragma unroll
        for (int df = 0; df < 4; ++df) {
            int col = h * 64 + df * 16 + (lane & 15);
            ctx[((size_t)(b * S_DIM + row)) * E_DIM + col] = f2bfh(o[df][q] * linv4[q]);
        }
    }
}

extern "C" void kernel_launch(void* const* d_in, const int* in_sizes, int n_in,
                              void* d_out, int out_size, void* d_ws, size_t ws_size,
                              hipStream_t stream) {
    const float* X  = (const float*)d_in[0];
    const float* Wq = (const float*)d_in[1];
    const float* Wk = (const float*)d_in[2];
    const float* Wv = (const float*)d_in[3];
    const float* Wo = (const float*)d_in[4];
    float* out = (float*)d_out;

    char* ws = (char*)d_ws;
    const size_t MB = (size_t)1 << 20;
    unsigned short* Xb  = (unsigned short*)(ws);            //  8 MB
    unsigned short* Wqt = (unsigned short*)(ws +  8 * MB);  //  2 MB
    unsigned short* Wkt = (unsigned short*)(ws + 10 * MB);
    unsigned short* Wvt = (unsigned short*)(ws + 12 * MB);
    unsigned short* Wot = (unsigned short*)(ws + 14 * MB);
    unsigned short* Qb  = (unsigned short*)(ws + 16 * MB);  //  8 MB each
    unsigned short* Kb  = (unsigned short*)(ws + 24 * MB);
    unsigned short* Vt  = (unsigned short*)(ws + 32 * MB);
    unsigned short* ctx = (unsigned short*)(ws + 40 * MB);  // ends at 48 MB

    prep<<<dim3(3072), 256, 0, stream>>>(X, Wq, Wk, Wv, Wo, Xb, Wqt, Wkt, Wvt, Wot);
    gemm_qkv<<<dim3(32, 8, 3), 256, 0, stream>>>(Xb, Wqt, Wkt, Wvt, Qb, Kb, Vt);
    attn<<<dim3(16, 32), 512, 0, stream>>>(Qb, Kb, Vt, ctx);
    gemm_out<<<dim3(32, 8), 256, 0, stream>>>(ctx, Wot, out);
}